// Round 3
// baseline (526.016 us; speedup 1.0000x reference)
//
#include <hip/hip_runtime.h>
#include <stdint.h>

// B=32 batch, K=1024 capsules, C=64 classes, O=32 out dim, I=32 in dim, 3 routing iters.
#define Bb 32
#define Kk 1024
#define Cc 64
#define Oo 32
#define Ii 32

typedef __attribute__((ext_vector_type(8))) short bf16x8;
typedef __attribute__((ext_vector_type(4))) float f32x4;

__device__ __forceinline__ short f2bf(float f) {
    uint32_t u = __builtin_bit_cast(uint32_t, f);
    u += 0x7fffu + ((u >> 16) & 1u);   // RNE (inputs finite)
    return (short)(u >> 16);
}
__device__ __forceinline__ float bflo(uint32_t u) { return __builtin_bit_cast(float, u << 16); }
__device__ __forceinline__ float bfhi(uint32_t u) { return __builtin_bit_cast(float, u & 0xffff0000u); }
__device__ __forceinline__ uint32_t pk2(float a, float b) {
    return (uint32_t)(uint16_t)f2bf(a) | ((uint32_t)(uint16_t)f2bf(b) << 16);
}

// uh layout (bf16 as dwords): dword = (k*64+c)*512 + half*256 + lane*4 + e.
// half0 = frag elems 0..7, half1 = elems 8..15. Elem i=t*4+r of lane (m,q):
// u_hat[b=(t&1)*16+m][o=(t>>1)*16+q*4+r]  (mfma_f32_16x16x32 C/D map).

__global__ __launch_bounds__(256) void k_uhat(const float* __restrict__ x,
                                              const float* __restrict__ W,
                                              uint32_t* __restrict__ uh) {
    const int k = blockIdx.x;
    const int lane = threadIdx.x & 63;
    const int wave = threadIdx.x >> 6;
    const int m = lane & 15;
    const int q = lane >> 4;

    bf16x8 bfrag[2];
#pragma unroll
    for (int nb = 0; nb < 2; ++nb) {
        const float* xp = x + (size_t)((nb * 16 + m) * Kk + k) * Ii + q * 8;
        f32x4 a = *(const f32x4*)xp;
        f32x4 b = *(const f32x4*)(xp + 4);
        bf16x8 t;
        t[0] = f2bf(a.x); t[1] = f2bf(a.y); t[2] = f2bf(a.z); t[3] = f2bf(a.w);
        t[4] = f2bf(b.x); t[5] = f2bf(b.y); t[6] = f2bf(b.z); t[7] = f2bf(b.w);
        bfrag[nb] = t;
    }

    for (int cc = 0; cc < 16; ++cc) {
        const int c = wave * 16 + cc;
        bf16x8 afrag[2];
#pragma unroll
        for (int mo = 0; mo < 2; ++mo) {
            const float* wp = W + (size_t)((k * Cc + c) * Oo + mo * 16 + m) * Ii + q * 8;
            f32x4 a = __builtin_nontemporal_load((const f32x4*)wp);
            f32x4 b = __builtin_nontemporal_load((const f32x4*)(wp + 4));
            bf16x8 t;
            t[0] = f2bf(a.x); t[1] = f2bf(a.y); t[2] = f2bf(a.z); t[3] = f2bf(a.w);
            t[4] = f2bf(b.x); t[5] = f2bf(b.y); t[6] = f2bf(b.z); t[7] = f2bf(b.w);
            afrag[mo] = t;
        }
        const f32x4 z = {0.f, 0.f, 0.f, 0.f};
        f32x4 d0 = __builtin_amdgcn_mfma_f32_16x16x32_bf16(afrag[0], bfrag[0], z, 0, 0, 0);
        f32x4 d1 = __builtin_amdgcn_mfma_f32_16x16x32_bf16(afrag[0], bfrag[1], z, 0, 0, 0);
        f32x4 d2 = __builtin_amdgcn_mfma_f32_16x16x32_bf16(afrag[1], bfrag[0], z, 0, 0, 0);
        f32x4 d3 = __builtin_amdgcn_mfma_f32_16x16x32_bf16(afrag[1], bfrag[1], z, 0, 0, 0);

        uint4 p0, p1;
        p0.x = pk2(d0.x, d0.y); p0.y = pk2(d0.z, d0.w);
        p0.z = pk2(d1.x, d1.y); p0.w = pk2(d1.z, d1.w);
        p1.x = pk2(d2.x, d2.y); p1.y = pk2(d2.z, d2.w);
        p1.z = pk2(d3.x, d3.y); p1.w = pk2(d3.z, d3.w);
        uint32_t* dst = uh + (size_t)(k * Cc + c) * 512 + lane * 4;
        *(uint4*)dst = p0;
        *(uint4*)(dst + 256) = p1;
    }
}

// iter0 s-partials (c uniform = 1/64): part0[chunk32][c][t][lane][r] fp32.
__global__ __launch_bounds__(256) void k_sacc0(const uint32_t* __restrict__ uh,
                                               float* __restrict__ part0) {
    const int lane = threadIdx.x & 63;
    const int wave = threadIdx.x >> 6;
    const int c = (blockIdx.x & 15) * 4 + wave;
    const int chunk = blockIdx.x >> 4;
    const int k0 = chunk * 32;

    float acc[16];
#pragma unroll
    for (int i = 0; i < 16; ++i) acc[i] = 0.f;

    for (int kl = 0; kl < 32; ++kl) {
        const uint32_t* up = uh + (size_t)((k0 + kl) * Cc + c) * 512 + lane * 4;
        uint4 q0 = *(const uint4*)up;
        uint4 q1 = *(const uint4*)(up + 256);
        const float w0 = 1.0f / 64.0f;
        acc[0]  += w0 * bflo(q0.x);  acc[1]  += w0 * bfhi(q0.x);
        acc[2]  += w0 * bflo(q0.y);  acc[3]  += w0 * bfhi(q0.y);
        acc[4]  += w0 * bflo(q0.z);  acc[5]  += w0 * bfhi(q0.z);
        acc[6]  += w0 * bflo(q0.w);  acc[7]  += w0 * bfhi(q0.w);
        acc[8]  += w0 * bflo(q1.x);  acc[9]  += w0 * bfhi(q1.x);
        acc[10] += w0 * bflo(q1.y);  acc[11] += w0 * bfhi(q1.y);
        acc[12] += w0 * bflo(q1.z);  acc[13] += w0 * bfhi(q1.z);
        acc[14] += w0 * bflo(q1.w);  acc[15] += w0 * bfhi(q1.w);
    }
#pragma unroll
    for (int t = 0; t < 4; ++t) {
        f32x4 v = {acc[t * 4 + 0], acc[t * 4 + 1], acc[t * 4 + 2], acc[t * 4 + 3]};
        *(f32x4*)&part0[(((size_t)(chunk * Cc + c) * 4 + t) * 64 + lane) * 4] = v;
    }
}

// reduce 32 fp32 chunk-partials + squash -> vfrag[c][lane][16]
__global__ __launch_bounds__(256) void k_reduce0(const float* __restrict__ part0,
                                                 float* __restrict__ vfrag) {
    __shared__ float red[4 * 64 * 17];
    const int c = blockIdx.x;
    const int tid = threadIdx.x;
    const int lane = tid & 63;
    const int cg = tid >> 6;

    float acc[16];
#pragma unroll
    for (int i = 0; i < 16; ++i) acc[i] = 0.f;
    for (int ch = cg * 8; ch < cg * 8 + 8; ++ch) {
        const f32x4* p = (const f32x4*)part0 + (size_t)(ch * Cc + c) * 4 * 64 + lane;
#pragma unroll
        for (int t = 0; t < 4; ++t) {
            f32x4 v = p[t * 64];
            acc[t * 4 + 0] += v.x; acc[t * 4 + 1] += v.y;
            acc[t * 4 + 2] += v.z; acc[t * 4 + 3] += v.w;
        }
    }
#pragma unroll
    for (int i = 0; i < 16; ++i) red[(cg * 64 + lane) * 17 + i] = acc[i];
    __syncthreads();

    if (tid < 64) {
        float a[16];
#pragma unroll
        for (int i = 0; i < 16; ++i)
            a[i] = red[tid * 17 + i] + red[(64 + tid) * 17 + i]
                 + red[(128 + tid) * 17 + i] + red[(192 + tid) * 17 + i];
        float sq0 = 0.f, sq1 = 0.f;
#pragma unroll
        for (int r = 0; r < 4; ++r) {
            sq0 += a[r] * a[r] + a[8 + r] * a[8 + r];
            sq1 += a[4 + r] * a[4 + r] + a[12 + r] * a[12 + r];
        }
        sq0 += __shfl_xor(sq0, 16); sq0 += __shfl_xor(sq0, 32);
        sq1 += __shfl_xor(sq1, 16); sq1 += __shfl_xor(sq1, 32);
        const float c0 = sq0 / ((1.f + sq0) * sqrtf(sq0 + 1e-8f));
        const float c1 = sq1 / ((1.f + sq1) * sqrtf(sq1 + 1e-8f));
#pragma unroll
        for (int r = 0; r < 4; ++r) {
            a[r] *= c0; a[8 + r] *= c0;
            a[4 + r] *= c1; a[12 + r] *= c1;
        }
        float* vp = vfrag + ((size_t)c * 64 + tid) * 16;
#pragma unroll
        for (int t = 0; t < 4; ++t) {
            f32x4 v = {a[t * 4 + 0], a[t * 4 + 1], a[t * 4 + 2], a[t * 4 + 3]};
            *(f32x4*)(vp + t * 4) = v;
        }
    }
}

// Fused routing iteration: agreement(v) -> b update -> softmax(c_ij in LDS)
// -> s-partial accumulation. Block: 4 k, all 64 c, 512 threads (8 waves).
// FINAL=false: iter1 (b_prev=0, write bbuf). FINAL=true: iter2 (read bbuf, write out_c).
// partB: bf16 pairs, dword = ((c*256+chunk)*64+lane)*8 + e.
template <bool FINAL>
__global__ __launch_bounds__(512) void k_iter(const uint32_t* __restrict__ uh,
                                              const float* __restrict__ vfrag,
                                              float* __restrict__ bbuf,    // [k][b][c]
                                              uint32_t* __restrict__ partB,
                                              float* __restrict__ outc) {  // [b][k][c]
    __shared__ float agr[4 * 64 * 32];
    const int tid = threadIdx.x;
    const int lane = tid & 63;
    const int w = tid >> 6;       // 0..7
    const int m = lane & 15;
    const int q = lane >> 4;
    const int k0 = blockIdx.x * 4;

    // Phase A: agreement for all (kl, c, b)
    for (int cc = 0; cc < 8; ++cc) {
        const int c = w * 8 + cc;
        const float* vp = vfrag + ((size_t)c * 64 + lane) * 16;
        f32x4 vv0 = *(const f32x4*)(vp);
        f32x4 vv1 = *(const f32x4*)(vp + 4);
        f32x4 vv2 = *(const f32x4*)(vp + 8);
        f32x4 vv3 = *(const f32x4*)(vp + 12);
#pragma unroll
        for (int kl = 0; kl < 4; ++kl) {
            const uint32_t* up = uh + (size_t)((k0 + kl) * Cc + c) * 512 + lane * 4;
            uint4 q0 = *(const uint4*)up;
            uint4 q1 = *(const uint4*)(up + 256);
            float p0 = bflo(q0.x) * vv0.x + bfhi(q0.x) * vv0.y
                     + bflo(q0.y) * vv0.z + bfhi(q0.y) * vv0.w
                     + bflo(q1.x) * vv2.x + bfhi(q1.x) * vv2.y
                     + bflo(q1.y) * vv2.z + bfhi(q1.y) * vv2.w;
            float p1 = bflo(q0.z) * vv1.x + bfhi(q0.z) * vv1.y
                     + bflo(q0.w) * vv1.z + bfhi(q0.w) * vv1.w
                     + bflo(q1.z) * vv3.x + bfhi(q1.z) * vv3.y
                     + bflo(q1.w) * vv3.z + bfhi(q1.w) * vv3.w;
            p0 += __shfl_xor(p0, 16);
            p0 += __shfl_xor(p0, 32);
            p1 += __shfl_xor(p1, 16);
            p1 += __shfl_xor(p1, 32);
            if (q == 0) {
                agr[(kl * 64 + c) * 32 + m] = p0;
                agr[(kl * 64 + c) * 32 + 16 + m] = p1;
            }
        }
    }
    __syncthreads();

    // Softmax over c per (k,b); b-logit update
    if (tid < 128) {
        const int kl = tid >> 5;
        const int b = tid & 31;
        const int k = k0 + kl;
        float row[64];
#pragma unroll
        for (int c = 0; c < 64; ++c) row[c] = agr[(kl * 64 + c) * 32 + b];
        if (!FINAL) {
            float* bp = bbuf + (size_t)(k * Bb + b) * Cc;
#pragma unroll
            for (int c = 0; c < 64; ++c) bp[c] = row[c];
        } else {
            const float* bp = bbuf + (size_t)(k * Bb + b) * Cc;
#pragma unroll
            for (int c = 0; c < 64; ++c) row[c] += bp[c];
        }
        float mx = row[0];
#pragma unroll
        for (int c = 1; c < 64; ++c) mx = fmaxf(mx, row[c]);
        float sum = 0.f;
#pragma unroll
        for (int c = 0; c < 64; ++c) { row[c] = __expf(row[c] - mx); sum += row[c]; }
        const float inv = 1.f / sum;
#pragma unroll
        for (int c = 0; c < 64; ++c) row[c] *= inv;
        if (FINAL) {
            float* op = outc + (size_t)(b * Kk + k) * Cc;
#pragma unroll
            for (int c = 0; c < 64; ++c) op[c] = row[c];
        }
#pragma unroll
        for (int c = 0; c < 64; ++c) agr[(kl * 64 + c) * 32 + b] = row[c];
    }
    __syncthreads();

    // Phase B: s-partials = sum over this block's 4 k of c_ij * u_hat
    const int chunk = blockIdx.x;
    for (int cg = 0; cg < 8; ++cg) {
        const int c = w * 8 + cg;
        float acc[16];
#pragma unroll
        for (int i = 0; i < 16; ++i) acc[i] = 0.f;
#pragma unroll
        for (int kl = 0; kl < 4; ++kl) {
            const uint32_t* up = uh + (size_t)((k0 + kl) * Cc + c) * 512 + lane * 4;
            uint4 q0 = *(const uint4*)up;
            uint4 q1 = *(const uint4*)(up + 256);
            const float w0 = agr[(kl * 64 + c) * 32 + m];
            const float w1 = agr[(kl * 64 + c) * 32 + 16 + m];
            acc[0]  += w0 * bflo(q0.x);  acc[1]  += w0 * bfhi(q0.x);
            acc[2]  += w0 * bflo(q0.y);  acc[3]  += w0 * bfhi(q0.y);
            acc[4]  += w1 * bflo(q0.z);  acc[5]  += w1 * bfhi(q0.z);
            acc[6]  += w1 * bflo(q0.w);  acc[7]  += w1 * bfhi(q0.w);
            acc[8]  += w0 * bflo(q1.x);  acc[9]  += w0 * bfhi(q1.x);
            acc[10] += w0 * bflo(q1.y);  acc[11] += w0 * bfhi(q1.y);
            acc[12] += w1 * bflo(q1.z);  acc[13] += w1 * bfhi(q1.z);
            acc[14] += w1 * bflo(q1.w);  acc[15] += w1 * bfhi(q1.w);
        }
        uint4 o0, o1;
        o0.x = pk2(acc[0],  acc[1]);  o0.y = pk2(acc[2],  acc[3]);
        o0.z = pk2(acc[4],  acc[5]);  o0.w = pk2(acc[6],  acc[7]);
        o1.x = pk2(acc[8],  acc[9]);  o1.y = pk2(acc[10], acc[11]);
        o1.z = pk2(acc[12], acc[13]); o1.w = pk2(acc[14], acc[15]);
        uint32_t* dst = partB + ((size_t)(c * 256 + chunk) * 64 + lane) * 8;
        *(uint4*)dst = o0;
        *(uint4*)(dst + 4) = o1;
    }
}

// Stage-1 reduce of 256 bf16 chunk-partials: block = (c, g of 8), sums 32 chunks.
__global__ __launch_bounds__(256) void k_red1(const uint32_t* __restrict__ partB,
                                              float* __restrict__ part2) {
    __shared__ float red[4 * 64 * 17];
    const int cb = blockIdx.x;          // c*8+g
    const int c = cb >> 3;
    const int g = cb & 7;
    const int tid = threadIdx.x;
    const int lane = tid & 63;
    const int ww = tid >> 6;

    float acc[16];
#pragma unroll
    for (int i = 0; i < 16; ++i) acc[i] = 0.f;
    for (int ch = g * 32 + ww * 8; ch < g * 32 + ww * 8 + 8; ++ch) {
        const uint32_t* p = partB + ((size_t)(c * 256 + ch) * 64 + lane) * 8;
        uint4 a = *(const uint4*)p;
        uint4 b = *(const uint4*)(p + 4);
        acc[0]  += bflo(a.x);  acc[1]  += bfhi(a.x);
        acc[2]  += bflo(a.y);  acc[3]  += bfhi(a.y);
        acc[4]  += bflo(a.z);  acc[5]  += bfhi(a.z);
        acc[6]  += bflo(a.w);  acc[7]  += bfhi(a.w);
        acc[8]  += bflo(b.x);  acc[9]  += bfhi(b.x);
        acc[10] += bflo(b.y);  acc[11] += bfhi(b.y);
        acc[12] += bflo(b.z);  acc[13] += bfhi(b.z);
        acc[14] += bflo(b.w);  acc[15] += bfhi(b.w);
    }
#pragma unroll
    for (int i = 0; i < 16; ++i) red[(ww * 64 + lane) * 17 + i] = acc[i];
    __syncthreads();

    if (tid < 64) {
        float a[16];
#pragma unroll
        for (int i = 0; i < 16; ++i)
            a[i] = red[tid * 17 + i] + red[(64 + tid) * 17 + i]
                 + red[(128 + tid) * 17 + i] + red[(192 + tid) * 17 + i];
        float* dst = part2 + ((size_t)cb * 64 + tid) * 16;
#pragma unroll
        for (int t = 0; t < 4; ++t) {
            f32x4 v = {a[t * 4 + 0], a[t * 4 + 1], a[t * 4 + 2], a[t * 4 + 3]};
            *(f32x4*)(dst + t * 4) = v;
        }
    }
}

// Stage-2: sum 8 fp32 partials + squash -> vfrag (+ out_v on FINAL).
template <bool FINAL>
__global__ __launch_bounds__(64) void k_red2(const float* __restrict__ part2,
                                             float* __restrict__ vfrag,
                                             float* __restrict__ out_v) {
    const int c = blockIdx.x;
    const int lane = threadIdx.x;
    const int m = lane & 15;
    const int q = lane >> 4;

    float a[16];
#pragma unroll
    for (int i = 0; i < 16; ++i) a[i] = 0.f;
    for (int g = 0; g < 8; ++g) {
        const float* p = part2 + ((size_t)(c * 8 + g) * 64 + lane) * 16;
#pragma unroll
        for (int t = 0; t < 4; ++t) {
            f32x4 v = *(const f32x4*)(p + t * 4);
            a[t * 4 + 0] += v.x; a[t * 4 + 1] += v.y;
            a[t * 4 + 2] += v.z; a[t * 4 + 3] += v.w;
        }
    }
    float sq0 = 0.f, sq1 = 0.f;
#pragma unroll
    for (int r = 0; r < 4; ++r) {
        sq0 += a[r] * a[r] + a[8 + r] * a[8 + r];
        sq1 += a[4 + r] * a[4 + r] + a[12 + r] * a[12 + r];
    }
    sq0 += __shfl_xor(sq0, 16); sq0 += __shfl_xor(sq0, 32);
    sq1 += __shfl_xor(sq1, 16); sq1 += __shfl_xor(sq1, 32);
    const float c0 = sq0 / ((1.f + sq0) * sqrtf(sq0 + 1e-8f));
    const float c1 = sq1 / ((1.f + sq1) * sqrtf(sq1 + 1e-8f));
#pragma unroll
    for (int r = 0; r < 4; ++r) {
        a[r] *= c0; a[8 + r] *= c0;
        a[4 + r] *= c1; a[12 + r] *= c1;
    }
    float* vp = vfrag + ((size_t)c * 64 + lane) * 16;
#pragma unroll
    for (int t = 0; t < 4; ++t) {
        f32x4 v = {a[t * 4 + 0], a[t * 4 + 1], a[t * 4 + 2], a[t * 4 + 3]};
        *(f32x4*)(vp + t * 4) = v;
    }
    if (FINAL) {
#pragma unroll
        for (int t = 0; t < 4; ++t)
#pragma unroll
            for (int r = 0; r < 4; ++r) {
                const int b = (t & 1) * 16 + m;
                const int o = (t >> 1) * 16 + q * 4 + r;
                out_v[((size_t)b * Cc + c) * Oo + o] = a[t * 4 + r];
            }
    }
}

extern "C" void kernel_launch(void* const* d_in, const int* in_sizes, int n_in,
                              void* d_out, int out_size, void* d_ws, size_t ws_size,
                              hipStream_t stream) {
    (void)in_sizes; (void)n_in; (void)out_size;
    const float* x = (const float*)d_in[0];
    const float* W = (const float*)d_in[1];
    float* out_v = (float*)d_out;                  // [B][C][O]
    float* out_c = out_v + Bb * Cc * Oo;           // [B][K][C]

    char* ws = (char*)d_ws;
    const size_t UH_BYTES = (size_t)Kk * Cc * 512 * 4;            // 128 MiB
    const size_t P0_BYTES = (size_t)32 * Cc * 4 * 64 * 4 * 4;     // 8 MiB
    const size_t PB_BYTES = (size_t)Cc * 256 * 64 * 8 * 4;        // 32 MiB
    const size_t P2_BYTES = (size_t)512 * 64 * 16 * 4;            // 2 MiB
    const size_t BB_BYTES = (size_t)Kk * Bb * Cc * 4;             // 8 MiB
    const size_t VF_BYTES = (size_t)Cc * 64 * 16 * 4;             // 256 KiB

    uint32_t* uh = (uint32_t*)ws;                      ws += UH_BYTES;
    float* part0  = (float*)ws;                        ws += P0_BYTES;
    uint32_t* partB = (uint32_t*)ws;                   ws += PB_BYTES;
    float* part2  = (float*)ws;                        ws += P2_BYTES;
    float* bbuf   = (float*)ws;                        ws += BB_BYTES;
    float* vfrag  = (float*)ws;                        ws += VF_BYTES;
    const size_t NEED = UH_BYTES + P0_BYTES + PB_BYTES + P2_BYTES + BB_BYTES + VF_BYTES;
    if (ws_size < NEED) return;

    k_uhat<<<Kk, 256, 0, stream>>>(x, W, uh);
    // iter 0: uniform c = 1/64
    k_sacc0<<<512, 256, 0, stream>>>(uh, part0);
    k_reduce0<<<Cc, 256, 0, stream>>>(part0, vfrag);
    // iter 1: agreement(v0) -> b1 -> softmax c1 -> s1 partials
    k_iter<false><<<256, 512, 0, stream>>>(uh, vfrag, bbuf, partB, nullptr);
    k_red1<<<512, 256, 0, stream>>>(partB, part2);
    k_red2<false><<<Cc, 64, 0, stream>>>(part2, vfrag, nullptr);
    // iter 2: agreement(v1) -> b2 -> softmax c2 (out_c) -> s2 partials
    k_iter<true><<<256, 512, 0, stream>>>(uh, vfrag, bbuf, partB, out_c);
    k_red1<<<512, 256, 0, stream>>>(partB, part2);
    k_red2<true><<<Cc, 64, 0, stream>>>(part2, vfrag, out_v);
}

// Round 4
// 507.819 us; speedup vs baseline: 1.0358x; 1.0358x over previous
//
#include <hip/hip_runtime.h>
#include <stdint.h>

// B=32 batch, K=1024 capsules, C=64 classes, O=32 out dim, I=32 in dim, 3 routing iters.
#define Bb 32
#define Kk 1024
#define Cc 64
#define Oo 32
#define Ii 32

typedef __attribute__((ext_vector_type(8))) short bf16x8;
typedef __attribute__((ext_vector_type(4))) float f32x4;

__device__ __forceinline__ short f2bf(float f) {
    uint32_t u = __builtin_bit_cast(uint32_t, f);
    u += 0x7fffu + ((u >> 16) & 1u);   // RNE (inputs finite)
    return (short)(u >> 16);
}
__device__ __forceinline__ float bflo(uint32_t u) { return __builtin_bit_cast(float, u << 16); }
__device__ __forceinline__ float bfhi(uint32_t u) { return __builtin_bit_cast(float, u & 0xffff0000u); }
__device__ __forceinline__ uint32_t pk2(float a, float b) {
    return (uint32_t)(uint16_t)f2bf(a) | ((uint32_t)(uint16_t)f2bf(b) << 16);
}

// uh layout (bf16 as dwords): dword = (k*64+c)*512 + half*256 + lane*4 + e.
// half0 = frag elems 0..7, half1 = elems 8..15. Elem i=t*4+r of lane (m,q):
// u_hat[b=(t&1)*16+m][o=(t>>1)*16+q*4+r]  (mfma_f32_16x16x32 C/D map).

// x transpose+convert: xT[k][b][i] bf16, dword = k*512 + b*16 + i/2.
__global__ __launch_bounds__(256) void k_xT(const float* __restrict__ x,
                                            uint32_t* __restrict__ xT) {
    const int k = blockIdx.x;
    const int tid = threadIdx.x;
    const int b = tid >> 3;
    const int i8 = (tid & 7) * 4;
    const float* xp = x + ((size_t)b * Kk + k) * Ii + i8;
    f32x4 v = *(const f32x4*)xp;
    uint32_t* dst = xT + (size_t)k * 512 + b * 16 + i8 / 2;
    dst[0] = pk2(v.x, v.y);
    dst[1] = pk2(v.z, v.w);
}

// u_hat + fused iter-0 s partials. Block = 4 waves; wave owns c = cgroup*4+wave,
// loops 16 k of its kchunk. part0[(kchunk*64+c)*64+lane][16] fp32 (raw sums; the
// 1/64 uniform-softmax weight is applied in k_redA).
__global__ __launch_bounds__(256) void k_uhat(const uint32_t* __restrict__ xT,
                                              const float* __restrict__ W,
                                              uint32_t* __restrict__ uh,
                                              float* __restrict__ part0) {
    const int kchunk = blockIdx.x & 63;
    const int cgroup = blockIdx.x >> 6;
    const int lane = threadIdx.x & 63;
    const int wave = threadIdx.x >> 6;
    const int c = cgroup * 4 + wave;
    const int m = lane & 15;
    const int q = lane >> 4;

    float acc[16];
#pragma unroll
    for (int i = 0; i < 16; ++i) acc[i] = 0.f;

    for (int kl = 0; kl < 16; ++kl) {
        const int k = kchunk * 16 + kl;
        // B frags: xT[k][nb*16+m][q*8..+8) -> 16 B/lane, coalesced, pre-bf16
        const uint32_t* xp = xT + (size_t)k * 512 + m * 16 + q * 4;
        bf16x8 b0 = *(const bf16x8*)xp;
        bf16x8 b1 = *(const bf16x8*)(xp + 256);
        // A frags: W[k][c][mo*16+m][q*8..+8) fp32, nontemporal (read-once)
        bf16x8 a0, a1;
        {
            const float* wp = W + (size_t)((k * Cc + c) * Oo + m) * Ii + q * 8;
            f32x4 u0 = __builtin_nontemporal_load((const f32x4*)wp);
            f32x4 u1 = __builtin_nontemporal_load((const f32x4*)(wp + 4));
            f32x4 u2 = __builtin_nontemporal_load((const f32x4*)(wp + 512));
            f32x4 u3 = __builtin_nontemporal_load((const f32x4*)(wp + 516));
            bf16x8 t;
            t[0] = f2bf(u0.x); t[1] = f2bf(u0.y); t[2] = f2bf(u0.z); t[3] = f2bf(u0.w);
            t[4] = f2bf(u1.x); t[5] = f2bf(u1.y); t[6] = f2bf(u1.z); t[7] = f2bf(u1.w);
            a0 = t;
            t[0] = f2bf(u2.x); t[1] = f2bf(u2.y); t[2] = f2bf(u2.z); t[3] = f2bf(u2.w);
            t[4] = f2bf(u3.x); t[5] = f2bf(u3.y); t[6] = f2bf(u3.z); t[7] = f2bf(u3.w);
            a1 = t;
        }
        const f32x4 z = {0.f, 0.f, 0.f, 0.f};
        f32x4 d0 = __builtin_amdgcn_mfma_f32_16x16x32_bf16(a0, b0, z, 0, 0, 0);
        f32x4 d1 = __builtin_amdgcn_mfma_f32_16x16x32_bf16(a0, b1, z, 0, 0, 0);
        f32x4 d2 = __builtin_amdgcn_mfma_f32_16x16x32_bf16(a1, b0, z, 0, 0, 0);
        f32x4 d3 = __builtin_amdgcn_mfma_f32_16x16x32_bf16(a1, b1, z, 0, 0, 0);

        uint4 p0, p1;
        p0.x = pk2(d0.x, d0.y); p0.y = pk2(d0.z, d0.w);
        p0.z = pk2(d1.x, d1.y); p0.w = pk2(d1.z, d1.w);
        p1.x = pk2(d2.x, d2.y); p1.y = pk2(d2.z, d2.w);
        p1.z = pk2(d3.x, d3.y); p1.w = pk2(d3.z, d3.w);
        uint32_t* dst = uh + (size_t)(k * Cc + c) * 512 + lane * 4;
        *(uint4*)dst = p0;
        *(uint4*)(dst + 256) = p1;

        acc[0]  += d0.x; acc[1]  += d0.y; acc[2]  += d0.z; acc[3]  += d0.w;
        acc[4]  += d1.x; acc[5]  += d1.y; acc[6]  += d1.z; acc[7]  += d1.w;
        acc[8]  += d2.x; acc[9]  += d2.y; acc[10] += d2.z; acc[11] += d2.w;
        acc[12] += d3.x; acc[13] += d3.y; acc[14] += d3.z; acc[15] += d3.w;
    }
#pragma unroll
    for (int t = 0; t < 4; ++t) {
        f32x4 v = {acc[t * 4 + 0], acc[t * 4 + 1], acc[t * 4 + 2], acc[t * 4 + 3]};
        *(f32x4*)&part0[(((size_t)(kchunk * Cc + c)) * 64 + lane) * 16 + t * 4] = v;
    }
}

// Reduce 64 fp32 kchunk-partials, scale by 1/64, squash -> vfrag[c][lane][16].
__global__ __launch_bounds__(256) void k_redA(const float* __restrict__ part0,
                                              float* __restrict__ vfrag) {
    __shared__ float red[4 * 64 * 17];
    const int c = blockIdx.x;
    const int tid = threadIdx.x;
    const int lane = tid & 63;
    const int grp = tid >> 6;

    float acc[16];
#pragma unroll
    for (int i = 0; i < 16; ++i) acc[i] = 0.f;
    for (int ch = grp * 16; ch < grp * 16 + 16; ++ch) {
        const float* p = part0 + (((size_t)(ch * Cc + c)) * 64 + lane) * 16;
#pragma unroll
        for (int t = 0; t < 4; ++t) {
            f32x4 v = *(const f32x4*)(p + t * 4);
            acc[t * 4 + 0] += v.x; acc[t * 4 + 1] += v.y;
            acc[t * 4 + 2] += v.z; acc[t * 4 + 3] += v.w;
        }
    }
#pragma unroll
    for (int i = 0; i < 16; ++i) red[(grp * 64 + lane) * 17 + i] = acc[i];
    __syncthreads();

    if (tid < 64) {
        float a[16];
#pragma unroll
        for (int i = 0; i < 16; ++i)
            a[i] = (red[tid * 17 + i] + red[(64 + tid) * 17 + i]
                  + red[(128 + tid) * 17 + i] + red[(192 + tid) * 17 + i]) * (1.f / 64.f);
        float sq0 = 0.f, sq1 = 0.f;
#pragma unroll
        for (int r = 0; r < 4; ++r) {
            sq0 += a[r] * a[r] + a[8 + r] * a[8 + r];
            sq1 += a[4 + r] * a[4 + r] + a[12 + r] * a[12 + r];
        }
        sq0 += __shfl_xor(sq0, 16); sq0 += __shfl_xor(sq0, 32);
        sq1 += __shfl_xor(sq1, 16); sq1 += __shfl_xor(sq1, 32);
        const float c0 = sq0 / ((1.f + sq0) * sqrtf(sq0 + 1e-8f));
        const float c1 = sq1 / ((1.f + sq1) * sqrtf(sq1 + 1e-8f));
#pragma unroll
        for (int r = 0; r < 4; ++r) {
            a[r] *= c0; a[8 + r] *= c0;
            a[4 + r] *= c1; a[12 + r] *= c1;
        }
        float* vp = vfrag + ((size_t)c * 64 + tid) * 16;
#pragma unroll
        for (int t = 0; t < 4; ++t) {
            f32x4 v = {a[t * 4 + 0], a[t * 4 + 1], a[t * 4 + 2], a[t * 4 + 3]};
            *(f32x4*)(vp + t * 4) = v;
        }
    }
}

// Fused routing iteration: agreement(v) -> b update -> softmax(c_ij in LDS)
// -> s-partial accumulation. Block: 4 k, all 64 c, 512 threads (8 waves).
template <bool FINAL>
__global__ __launch_bounds__(512) void k_iter(const uint32_t* __restrict__ uh,
                                              const float* __restrict__ vfrag,
                                              float* __restrict__ bbuf,    // [k][b][c]
                                              uint32_t* __restrict__ partB,
                                              float* __restrict__ outc) {  // [b][k][c]
    __shared__ float agr[4 * 64 * 32];
    const int tid = threadIdx.x;
    const int lane = tid & 63;
    const int w = tid >> 6;       // 0..7
    const int m = lane & 15;
    const int q = lane >> 4;
    const int k0 = blockIdx.x * 4;

    for (int cc = 0; cc < 8; ++cc) {
        const int c = w * 8 + cc;
        const float* vp = vfrag + ((size_t)c * 64 + lane) * 16;
        f32x4 vv0 = *(const f32x4*)(vp);
        f32x4 vv1 = *(const f32x4*)(vp + 4);
        f32x4 vv2 = *(const f32x4*)(vp + 8);
        f32x4 vv3 = *(const f32x4*)(vp + 12);
#pragma unroll
        for (int kl = 0; kl < 4; ++kl) {
            const uint32_t* up = uh + (size_t)((k0 + kl) * Cc + c) * 512 + lane * 4;
            uint4 q0 = *(const uint4*)up;
            uint4 q1 = *(const uint4*)(up + 256);
            float p0 = bflo(q0.x) * vv0.x + bfhi(q0.x) * vv0.y
                     + bflo(q0.y) * vv0.z + bfhi(q0.y) * vv0.w
                     + bflo(q1.x) * vv2.x + bfhi(q1.x) * vv2.y
                     + bflo(q1.y) * vv2.z + bfhi(q1.y) * vv2.w;
            float p1 = bflo(q0.z) * vv1.x + bfhi(q0.z) * vv1.y
                     + bflo(q0.w) * vv1.z + bfhi(q0.w) * vv1.w
                     + bflo(q1.z) * vv3.x + bfhi(q1.z) * vv3.y
                     + bflo(q1.w) * vv3.z + bfhi(q1.w) * vv3.w;
            p0 += __shfl_xor(p0, 16);
            p0 += __shfl_xor(p0, 32);
            p1 += __shfl_xor(p1, 16);
            p1 += __shfl_xor(p1, 32);
            if (q == 0) {
                agr[(kl * 64 + c) * 32 + m] = p0;
                agr[(kl * 64 + c) * 32 + 16 + m] = p1;
            }
        }
    }
    __syncthreads();

    if (tid < 128) {
        const int kl = tid >> 5;
        const int b = tid & 31;
        const int k = k0 + kl;
        float row[64];
#pragma unroll
        for (int c = 0; c < 64; ++c) row[c] = agr[(kl * 64 + c) * 32 + b];
        if (!FINAL) {
            float* bp = bbuf + (size_t)(k * Bb + b) * Cc;
#pragma unroll
            for (int c = 0; c < 64; ++c) bp[c] = row[c];
        } else {
            const float* bp = bbuf + (size_t)(k * Bb + b) * Cc;
#pragma unroll
            for (int c = 0; c < 64; ++c) row[c] += bp[c];
        }
        float mx = row[0];
#pragma unroll
        for (int c = 1; c < 64; ++c) mx = fmaxf(mx, row[c]);
        float sum = 0.f;
#pragma unroll
        for (int c = 0; c < 64; ++c) { row[c] = __expf(row[c] - mx); sum += row[c]; }
        const float inv = 1.f / sum;
#pragma unroll
        for (int c = 0; c < 64; ++c) row[c] *= inv;
        if (FINAL) {
            float* op = outc + (size_t)(b * Kk + k) * Cc;
#pragma unroll
            for (int c = 0; c < 64; ++c) op[c] = row[c];
        }
#pragma unroll
        for (int c = 0; c < 64; ++c) agr[(kl * 64 + c) * 32 + b] = row[c];
    }
    __syncthreads();

    const int chunk = blockIdx.x;
    for (int cg = 0; cg < 8; ++cg) {
        const int c = w * 8 + cg;
        float acc[16];
#pragma unroll
        for (int i = 0; i < 16; ++i) acc[i] = 0.f;
#pragma unroll
        for (int kl = 0; kl < 4; ++kl) {
            const uint32_t* up = uh + (size_t)((k0 + kl) * Cc + c) * 512 + lane * 4;
            uint4 q0 = *(const uint4*)up;
            uint4 q1 = *(const uint4*)(up + 256);
            const float w0 = agr[(kl * 64 + c) * 32 + m];
            const float w1 = agr[(kl * 64 + c) * 32 + 16 + m];
            acc[0]  += w0 * bflo(q0.x);  acc[1]  += w0 * bfhi(q0.x);
            acc[2]  += w0 * bflo(q0.y);  acc[3]  += w0 * bfhi(q0.y);
            acc[4]  += w1 * bflo(q0.z);  acc[5]  += w1 * bfhi(q0.z);
            acc[6]  += w1 * bflo(q0.w);  acc[7]  += w1 * bfhi(q0.w);
            acc[8]  += w0 * bflo(q1.x);  acc[9]  += w0 * bfhi(q1.x);
            acc[10] += w0 * bflo(q1.y);  acc[11] += w0 * bfhi(q1.y);
            acc[12] += w1 * bflo(q1.z);  acc[13] += w1 * bfhi(q1.z);
            acc[14] += w1 * bflo(q1.w);  acc[15] += w1 * bfhi(q1.w);
        }
        uint4 o0, o1;
        o0.x = pk2(acc[0],  acc[1]);  o0.y = pk2(acc[2],  acc[3]);
        o0.z = pk2(acc[4],  acc[5]);  o0.w = pk2(acc[6],  acc[7]);
        o1.x = pk2(acc[8],  acc[9]);  o1.y = pk2(acc[10], acc[11]);
        o1.z = pk2(acc[12], acc[13]); o1.w = pk2(acc[14], acc[15]);
        uint32_t* dst = partB + ((size_t)(c * 256 + chunk) * 64 + lane) * 8;
        *(uint4*)dst = o0;
        *(uint4*)(dst + 4) = o1;
    }
}

// Stage-1 reduce of 256 bf16 chunk-partials: block = (c, g of 8), sums 32 chunks.
__global__ __launch_bounds__(256) void k_red1(const uint32_t* __restrict__ partB,
                                              float* __restrict__ part2) {
    __shared__ float red[4 * 64 * 17];
    const int cb = blockIdx.x;          // c*8+g
    const int c = cb >> 3;
    const int g = cb & 7;
    const int tid = threadIdx.x;
    const int lane = tid & 63;
    const int ww = tid >> 6;

    float acc[16];
#pragma unroll
    for (int i = 0; i < 16; ++i) acc[i] = 0.f;
    for (int ch = g * 32 + ww * 8; ch < g * 32 + ww * 8 + 8; ++ch) {
        const uint32_t* p = partB + ((size_t)(c * 256 + ch) * 64 + lane) * 8;
        uint4 a = *(const uint4*)p;
        uint4 b = *(const uint4*)(p + 4);
        acc[0]  += bflo(a.x);  acc[1]  += bfhi(a.x);
        acc[2]  += bflo(a.y);  acc[3]  += bfhi(a.y);
        acc[4]  += bflo(a.z);  acc[5]  += bfhi(a.z);
        acc[6]  += bflo(a.w);  acc[7]  += bfhi(a.w);
        acc[8]  += bflo(b.x);  acc[9]  += bfhi(b.x);
        acc[10] += bflo(b.y);  acc[11] += bfhi(b.y);
        acc[12] += bflo(b.z);  acc[13] += bfhi(b.z);
        acc[14] += bflo(b.w);  acc[15] += bfhi(b.w);
    }
#pragma unroll
    for (int i = 0; i < 16; ++i) red[(ww * 64 + lane) * 17 + i] = acc[i];
    __syncthreads();

    if (tid < 64) {
        float a[16];
#pragma unroll
        for (int i = 0; i < 16; ++i)
            a[i] = red[tid * 17 + i] + red[(64 + tid) * 17 + i]
                 + red[(128 + tid) * 17 + i] + red[(192 + tid) * 17 + i];
        float* dst = part2 + ((size_t)cb * 64 + tid) * 16;
#pragma unroll
        for (int t = 0; t < 4; ++t) {
            f32x4 v = {a[t * 4 + 0], a[t * 4 + 1], a[t * 4 + 2], a[t * 4 + 3]};
            *(f32x4*)(dst + t * 4) = v;
        }
    }
}

// Stage-2: sum 8 fp32 partials + squash -> vfrag (+ out_v on FINAL).
template <bool FINAL>
__global__ __launch_bounds__(64) void k_red2(const float* __restrict__ part2,
                                             float* __restrict__ vfrag,
                                             float* __restrict__ out_v) {
    const int c = blockIdx.x;
    const int lane = threadIdx.x;
    const int m = lane & 15;
    const int q = lane >> 4;

    float a[16];
#pragma unroll
    for (int i = 0; i < 16; ++i) a[i] = 0.f;
    for (int g = 0; g < 8; ++g) {
        const float* p = part2 + ((size_t)(c * 8 + g) * 64 + lane) * 16;
#pragma unroll
        for (int t = 0; t < 4; ++t) {
            f32x4 v = *(const f32x4*)(p + t * 4);
            a[t * 4 + 0] += v.x; a[t * 4 + 1] += v.y;
            a[t * 4 + 2] += v.z; a[t * 4 + 3] += v.w;
        }
    }
    float sq0 = 0.f, sq1 = 0.f;
#pragma unroll
    for (int r = 0; r < 4; ++r) {
        sq0 += a[r] * a[r] + a[8 + r] * a[8 + r];
        sq1 += a[4 + r] * a[4 + r] + a[12 + r] * a[12 + r];
    }
    sq0 += __shfl_xor(sq0, 16); sq0 += __shfl_xor(sq0, 32);
    sq1 += __shfl_xor(sq1, 16); sq1 += __shfl_xor(sq1, 32);
    const float c0 = sq0 / ((1.f + sq0) * sqrtf(sq0 + 1e-8f));
    const float c1 = sq1 / ((1.f + sq1) * sqrtf(sq1 + 1e-8f));
#pragma unroll
    for (int r = 0; r < 4; ++r) {
        a[r] *= c0; a[8 + r] *= c0;
        a[4 + r] *= c1; a[12 + r] *= c1;
    }
    float* vp = vfrag + ((size_t)c * 64 + lane) * 16;
#pragma unroll
    for (int t = 0; t < 4; ++t) {
        f32x4 v = {a[t * 4 + 0], a[t * 4 + 1], a[t * 4 + 2], a[t * 4 + 3]};
        *(f32x4*)(vp + t * 4) = v;
    }
    if (FINAL) {
#pragma unroll
        for (int t = 0; t < 4; ++t)
#pragma unroll
            for (int r = 0; r < 4; ++r) {
                const int b = (t & 1) * 16 + m;
                const int o = (t >> 1) * 16 + q * 4 + r;
                out_v[((size_t)b * Cc + c) * Oo + o] = a[t * 4 + r];
            }
    }
}

extern "C" void kernel_launch(void* const* d_in, const int* in_sizes, int n_in,
                              void* d_out, int out_size, void* d_ws, size_t ws_size,
                              hipStream_t stream) {
    (void)in_sizes; (void)n_in; (void)out_size;
    const float* x = (const float*)d_in[0];
    const float* W = (const float*)d_in[1];
    float* out_v = (float*)d_out;                  // [B][C][O]
    float* out_c = out_v + Bb * Cc * Oo;           // [B][K][C]

    char* ws = (char*)d_ws;
    const size_t UH_BYTES = (size_t)Kk * Cc * 512 * 4;            // 128 MiB
    const size_t XT_BYTES = (size_t)Kk * 512 * 4;                 // 2 MiB
    const size_t P0_BYTES = (size_t)64 * Cc * 64 * 16 * 4;        // 16 MiB
    const size_t PB_BYTES = (size_t)Cc * 256 * 64 * 8 * 4;        // 32 MiB
    const size_t P2_BYTES = (size_t)512 * 64 * 16 * 4;            // 2 MiB
    const size_t BB_BYTES = (size_t)Kk * Bb * Cc * 4;             // 8 MiB
    const size_t VF_BYTES = (size_t)Cc * 64 * 16 * 4;             // 256 KiB

    uint32_t* uh = (uint32_t*)ws;                      ws += UH_BYTES;
    uint32_t* xT = (uint32_t*)ws;                      ws += XT_BYTES;
    float* part0  = (float*)ws;                        ws += P0_BYTES;
    uint32_t* partB = (uint32_t*)ws;                   ws += PB_BYTES;
    float* part2  = (float*)ws;                        ws += P2_BYTES;
    float* bbuf   = (float*)ws;                        ws += BB_BYTES;
    float* vfrag  = (float*)ws;                        ws += VF_BYTES;
    const size_t NEED = UH_BYTES + XT_BYTES + P0_BYTES + PB_BYTES + P2_BYTES + BB_BYTES + VF_BYTES;
    if (ws_size < NEED) return;

    k_xT<<<Kk, 256, 0, stream>>>(x, xT);
    // u_hat + fused iter-0 s partials
    k_uhat<<<1024, 256, 0, stream>>>(xT, W, uh, part0);
    k_redA<<<Cc, 256, 0, stream>>>(part0, vfrag);            // v0
    // iter 1: agreement(v0) -> b1 -> softmax c1 -> s1 partials
    k_iter<false><<<256, 512, 0, stream>>>(uh, vfrag, bbuf, partB, nullptr);
    k_red1<<<512, 256, 0, stream>>>(partB, part2);
    k_red2<false><<<Cc, 64, 0, stream>>>(part2, vfrag, nullptr);   // v1
    // iter 2: agreement(v1) -> b2 -> softmax c2 (out_c) -> s2 partials
    k_iter<true><<<256, 512, 0, stream>>>(uh, vfrag, bbuf, partB, out_c);
    k_red1<<<512, 256, 0, stream>>>(partB, part2);
    k_red2<true><<<Cc, 64, 0, stream>>>(part2, vfrag, out_v);      // v2 = out_v
}